// Round 23
// baseline (301.155 us; speedup 1.0000x reference)
//
#include <hip/hip_runtime.h>
#include <stdint.h>

#define SEQ 8192
#define CS 64                       // chunk length == block row tile
#define NCH 128                     // chunks per sequence
#define QB2 8                       // batches per quarter
#define QBLK (QB2 * NCH)            // 1024 blocks per quarter dispatch

typedef float f32x4 __attribute__((ext_vector_type(4)));
typedef short short8 __attribute__((ext_vector_type(8)));
typedef unsigned short u16;
typedef u16 ushort8 __attribute__((ext_vector_type(8)));
typedef u16 ushort4v __attribute__((ext_vector_type(4)));

__device__ __forceinline__ u16 f2bf(float f) {
  uint32_t u = __float_as_uint(f);
  u += 0x7fffu + ((u >> 16) & 1u);   // round-to-nearest-even
  return (u16)(u >> 16);
}
__device__ __forceinline__ float bf2f(uint32_t lo16) {
  return __uint_as_float(lo16 << 16);
}

// async 16B global->LDS (lds dest wave-uniform base; HW adds lane*16)
__device__ __forceinline__ void gld16(void* lds, const void* g) {
  __builtin_amdgcn_global_load_lds(
      (const __attribute__((address_space(1))) uint32_t*)g,
      (__attribute__((address_space(3))) uint32_t*)lds, 16, 0, 0);
}

// ---------- emb f32 -> bf16 table (one-time) ----------
__global__ void embq_kernel(const float* __restrict__ emb, u16* __restrict__ embq) {
  int i = (blockIdx.x * 256 + threadIdx.x) * 4;   // 8,192,000 elements exactly
  float4 v = *(const float4*)(emb + i);
  ushort4v p;
  p[0] = f2bf(v.x); p[1] = f2bf(v.y); p[2] = f2bf(v.z); p[3] = f2bf(v.w);
  *(ushort4v*)(embq + i) = p;
}

// ---------- weight preprocess: f32 [l][k][d] -> bf16 swizzled 4KB BK=32 tiles ----------
// WtS: 128 tiles of 4096 BYTES, tile index (mat*4 + dh)*8 + k32, in-tile [64 dloc][32 kl],
// byte = dloc*64 + ((kl*2) ^ (((dloc>>1)&3)<<4)).  mat: 0=Wz l0,1=Wz l1,2=Wh l0,3=Wh l1
__global__ void wt_kernel(const float* __restrict__ Wz, const float* __restrict__ Wh,
                          u16* __restrict__ WtS) {
  int idx = blockIdx.x * 256 + threadIdx.x;   // 4*65536
  int d = idx & 255;
  int k = (idx >> 8) & 255;
  int m = idx >> 16;
  const float* src = (m < 2 ? Wz : Wh) + (size_t)(m & 1) * 65536;
  float v = src[k * 256 + d];
  int dh = d >> 6, dloc = d & 63, k32 = k >> 5, kl = k & 31;
  size_t tile = ((size_t)(m * 4 + dh) * 8 + k32) * 4096;   // BYTES
  size_t byte = (size_t)(dloc * 64 + ((kl * 2) ^ (((dloc >> 1) & 3) << 4)));
  *(u16*)((char*)WtS + tile + byte) = f2bf(v);
}

// ---- stage ONE wave's private 4KB dh-tile (dh = wave id) for (mat, k32): 4 gld16 ----
__device__ __forceinline__ void stage32(char* dst_wave, const char* WtSb, int mat, int k32,
                                        int w, int lane) {
  const char* src = WtSb + ((size_t)((mat * 4 + w) * 8 + k32)) * 4096 + lane * 16;
  #pragma unroll
  for (int i = 0; i < 4; i++)
    gld16(dst_wave + i * 1024, src + i * 1024);
}

// ---- A-fragment load for one k32: 4 m-frags covering all 64 rows ----
__device__ __forceinline__ void load_fa(const u16* As, int k32, int l15, int lg,
                                        short8 (&fa)[4]) {
  const int xm = (l15 & 7) << 4;
  const int kt = k32 >> 1, ks = k32 & 1;
  #pragma unroll
  for (int mi = 0; mi < 4; mi++)
    fa[mi] = *(const short8*)((const char*)As + kt * 8192 +
               (((mi * 16 + l15) * 128 + ks * 64 + lg * 16) ^ xm));
}

// ---- one 32-k MFMA step (16 MFMAs/wave) from the wave's private 4KB B tile ----
__device__ __forceinline__ void mfma_frags(const char* Pw, const short8 (&fa)[4],
    int l15, int lg, f32x4 (&acc)[4][4])
{
  #pragma unroll
  for (int ni = 0; ni < 4; ni++) {
    const int dloc = ni * 16 + l15;
    const int off = dloc * 64 + ((lg * 16) ^ (((dloc >> 1) & 3) << 4));
    short8 fb = *(const short8*)(Pw + off);
    #pragma unroll
    for (int mi = 0; mi < 4; mi++)
      acc[mi][ni] = __builtin_amdgcn_mfma_f32_16x16x32_bf16(fa[mi], fb, acc[mi][ni], 0, 0, 0);
  }
}

// ---- barrier-free tri-buffered counted-vmcnt pipeline (r17/r20 validated) ----
__device__ __forceinline__ void gemm_pipe3(int lsel, const char* WtSb, const u16* As,
    char* Pw, int w, int l15, int lg, int lane,
    f32x4 (&accz)[4][4], f32x4 (&acch)[4][4])
{
  stage32(Pw,         WtSb, lsel,     0, w, lane);   // j=0 (z, k32=0) -> buf0
  stage32(Pw + 16384, WtSb, 2 + lsel, 0, w, lane);   // j=1 (h, k32=0) -> buf1
  short8 fa[4];
  #pragma unroll
  for (int i = 0; i < 16; ++i) {
    if (i < 15) asm volatile("s_waitcnt vmcnt(4)" ::: "memory");
    else        asm volatile("s_waitcnt vmcnt(0)" ::: "memory");
    __builtin_amdgcn_sched_barrier(0);               // keep reads below the wait
    if (i + 2 < 16)
      stage32(Pw + ((i + 2) % 3) * 16384, WtSb,
              ((i + 2) & 1) ? (2 + lsel) : lsel, (i + 2) >> 1, w, lane);
    if ((i & 1) == 0) {
      load_fa(As, i >> 1, l15, lg, fa);
      mfma_frags(Pw + (i % 3) * 16384, fa, l15, lg, accz);
    } else {
      mfma_frags(Pw + (i % 3) * 16384, fa, l15, lg, acch);
    }
  }
}

// SegT addressing (overlays As): seg row 2048B, XOR-swizzled by seg to spread banks
__device__ __forceinline__ float2* seg_ptr(char* segt, int s, int d) {
  return (float2*)(segt + s * 2048 + ((d * 8) ^ (s << 4)));
}

// ab layout (coalesced, r21-validated): element index within block (u32 units):
//   t = mi*16 + lg*4 + r,  d = w*64 + ni*16 + l15
//   L = (mi*64 + r*16 + ni*4 + w)*64 + lg*16 + l15
// -> gate-loop store (fixed mi,ni,r; lanes lg,l15) covers 64 consecutive u32 = 256B.

// ---------- unified GEMM kernel (per-quarter) ----------
// Block: 256 threads (4 waves; wave w owns ALL 64 rows x cols [64w, 64w+64)), K=256.
// PHASE 0: embq gather -> gemm0 -> gates -> packed ab STORE + chunk totals -> Ap0/Bs0.
// PHASE 1: rebuild h1 from ab+carry (serial per channel) -> gemm1 -> gates -> Ap1/Bs1.
template<int PHASE>
__global__ __launch_bounds__(256, 2)
void gru_kernel(const int* __restrict__ x, const u16* __restrict__ embq,
                const u16* __restrict__ WtS,
                const float* __restrict__ bz0, const float* __restrict__ bh0,
                const float* __restrict__ bz1, const float* __restrict__ bh1,
                const float* __restrict__ carry, uint32_t* __restrict__ ab,
                float* __restrict__ Ap, float* __restrict__ Bs)
{
  __shared__ __align__(16) u16 As[16384];    // 32KB: 4 kt-subtiles [64t][64k] swz; SegT overlay
  __shared__ __align__(16) char Pb[49152];   // 48KB: 3 bufs x (4 waves x 4KB private)

  const int tid = threadIdx.x;
  const int lane = tid & 63;
  const int w = tid >> 6;                    // wave = col-group, owns d in [64w, 64w+64)
  const int l15 = lane & 15, lg = lane >> 4;
  const int cb = blockIdx.x;                 // 0..QBLK-1 (local to quarter)
  const int b = cb >> 7, c = cb & (NCH - 1);
  const char* WtSb = (const char*)WtS;
  char* segt = (char*)As;
  char* Pw = Pb + w * 4096;                  // wave's private region within each 16KB buf

  f32x4 accz[4][4], acch[4][4];
  #pragma unroll
  for (int i = 0; i < 4; i++)
    #pragma unroll
    for (int j = 0; j < 4; j++) {
      f32x4 zz = {0.f, 0.f, 0.f, 0.f};
      accz[i][j] = zz; acch[i][j] = zz;
    }

  if (PHASE == 0) {
    // ---- A gather: 64 rows x 256 k; thread = (row sm=tid>>2, 64-k quarter kq=tid&3) ----
    {
      const int sm = tid >> 2, kq = tid & 3;
      const int tok = x[b * SEQ + c * CS + sm];
      const u16* src = embq + (size_t)tok * 256 + kq * 64;
      char* sub = (char*)As + kq * 8192;
      const int swz = (sm & 7) << 4;
      #pragma unroll
      for (int j = 0; j < 8; j++) {
        ushort8 p = *(const ushort8*)(src + j * 8);
        *(ushort8*)(sub + ((sm * 128 + j * 16) ^ swz)) = p;
      }
    }
    __syncthreads();                         // As ready (drains vmcnt -> 0 at pipe entry)
    gemm_pipe3(0, WtSb, As, Pw, w, l15, lg, lane, accz, acch);
    __syncthreads();                         // all MFMA done; As free for SegT

    // ---- gates -> coalesced ab store + per-segment (A,B) -> SegT ----
    #pragma unroll
    for (int ni = 0; ni < 4; ni++) {
      const int d = w * 64 + ni * 16 + l15;
      const float bzv = bz0[d];
      const float bhv = bh0[d];
      #pragma unroll
      for (int mi = 0; mi < 4; mi++) {
        float A = 1.f, B = 0.f;
        #pragma unroll
        for (int r = 0; r < 4; r++) {
          float zl = accz[mi][ni][r] + bzv;
          float a = __builtin_amdgcn_rcpf(1.f + __expf(zl));   // 1 - sigmoid(zl)
          float ht = acch[mi][ni][r] + bhv;
          float bb = (1.f - a) * ht;
          ab[(size_t)cb * 16384 + (size_t)((mi * 64 + r * 16 + ni * 4 + w) * 64 + lg * 16 + l15)] =
              (uint32_t)f2bf(a) | ((uint32_t)f2bf(bb) << 16);
          B = B * a + bb;
          A *= a;
        }
        *seg_ptr(segt, mi * 4 + lg, d) = make_float2(A, B);    // seg = t/4
      }
    }
    __syncthreads();                         // SegT complete
    {
      float PA = 1.f, PB = 0.f;              // all 256 threads: d = tid
      #pragma unroll
      for (int s = 0; s < 16; s++) {
        float2 v = *seg_ptr(segt, s, tid);
        PB = v.x * PB + v.y;
        PA *= v.x;
      }
      Ap[(size_t)cb * 256 + tid] = PA;
      Bs[(size_t)cb * 256 + tid] = PB;
    }
    return;
  }

  // ================= PHASE 1 =================
  // ---- rebuild h1 tile into As from ab + carry (thread owns channel d = tid) ----
  {
    const int d = tid;
    float h = carry[(size_t)cb * 256 + d];
    const uint32_t* pab = ab + (size_t)cb * 16384 +
                          (size_t)((((d >> 4) & 3) * 4 + (d >> 6)) * 64 + (d & 15));
    char* sub = (char*)As + (d >> 6) * 8192;
    const int kl2 = (d & 63) * 2;
    #pragma unroll
    for (int t = 0; t < CS; t++) {
      uint32_t u = pab[(t >> 4) * 4096 + (t & 3) * 1024 + ((t >> 2) & 3) * 16];
      h = bf2f(u & 0xffffu) * h + bf2f(u >> 16);
      *(u16*)(sub + ((t * 128 + kl2) ^ ((t & 7) << 4))) = f2bf(h);
    }
  }
  __syncthreads();                           // h-tile ready (drains vmcnt -> 0)
  gemm_pipe3(1, WtSb, As, Pw, w, l15, lg, lane, accz, acch);
  __syncthreads();                           // As free for SegT

  // ---- layer-1 gates -> SegT -> totals -> Ap1/Bs1 ----
  #pragma unroll
  for (int ni = 0; ni < 4; ni++) {
    const int d = w * 64 + ni * 16 + l15;
    const float bzv = bz1[d];
    const float bhv = bh1[d];
    #pragma unroll
    for (int mi = 0; mi < 4; mi++) {
      float A = 1.f, B = 0.f;
      #pragma unroll
      for (int r = 0; r < 4; r++) {
        float zl = accz[mi][ni][r] + bzv;
        float a = __builtin_amdgcn_rcpf(1.f + __expf(zl));
        float ht = acch[mi][ni][r] + bhv;
        float bb = (1.f - a) * ht;
        B = B * a + bb;
        A *= a;
      }
      *seg_ptr(segt, mi * 4 + lg, d) = make_float2(A, B);
    }
  }
  __syncthreads();
  {
    float PA = 1.f, PB = 0.f;
    #pragma unroll
    for (int s = 0; s < 16; s++) {
      float2 v = *seg_ptr(segt, s, tid);
      PB = v.x * PB + v.y;
      PA *= v.x;
    }
    Ap[(size_t)cb * 256 + tid] = PA;
    Bs[(size_t)cb * 256 + tid] = PB;
  }
}

// ---------- serial cross-chunk compose for one quarter (8 batches) ----------
__global__ void scan2_l0(const float* __restrict__ Ap0, const float* __restrict__ Bs0,
                         float* __restrict__ carry) {
  const int g = blockIdx.x * 256 + threadIdx.x;   // 2048 = 8 b * 256 d
  const int b = g >> 8, d = g & 255;
  float h = 0.f;
  for (int c = 0; c < NCH; c++) {
    const size_t idx = (size_t)(b * NCH + c) * 256 + d;
    carry[idx] = h;
    h = Bs0[idx] + Ap0[idx] * h;
  }
}

// ---------- layer-1 final: serial over chunk locals -> hlast (all 32 batches) ----------
__global__ void scan2_l1(const float* __restrict__ Ap1, const float* __restrict__ Bs1,
                         float* __restrict__ hlast) {
  const int g = blockIdx.x * 256 + threadIdx.x;   // 8192
  const int b = g >> 8, d = g & 255;
  float h = 0.f;
  for (int c = 0; c < NCH; c++) {
    const size_t idx = (size_t)(b * NCH + c) * 256 + d;
    h = Bs1[idx] + Ap1[idx] * h;
  }
  hlast[b * 256 + d] = h;
}

__global__ void cls_kernel(const float* __restrict__ hlast, const float* __restrict__ Wo,
                           const float* __restrict__ bo, float* __restrict__ out) {
  const int t = threadIdx.x;       // 256 = 32 b * 8 classes
  const int b = t >> 3, c = t & 7;
  float acc = bo[c];
  for (int d = 0; d < 256; d++) acc += hlast[b * 256 + d] * Wo[d * 8 + c];
  out[t] = acc;
}

extern "C" void kernel_launch(void* const* d_in, const int* in_sizes, int n_in,
                              void* d_out, int out_size, void* d_ws, size_t ws_size,
                              hipStream_t stream) {
  (void)in_sizes; (void)n_in; (void)out_size; (void)ws_size;
  const int*   x   = (const int*)d_in[0];
  const float* emb = (const float*)d_in[1];
  const float* Wz  = (const float*)d_in[2];
  const float* bz  = (const float*)d_in[3];
  const float* Wh  = (const float*)d_in[4];
  const float* bh  = (const float*)d_in[5];
  const float* Wo  = (const float*)d_in[6];
  const float* bo  = (const float*)d_in[7];
  float* out = (float*)d_out;
  char* ws = (char*)d_ws;

  // workspace (~99 MB; ws = 256 MiB)
  u16*      embq  = (u16*)     (ws);                  // 16,384,000 (pad to 16 MiB)
  u16*      WtS   = (u16*)     (ws + 16777216ull);    //    524,288
  float*    Ap0   = (float*)   (ws + 17301504ull);    //  1,048,576 (quarter-local)
  float*    Bs0   = (float*)   (ws + 18350080ull);    //  1,048,576
  float*    carry = (float*)   (ws + 19398656ull);    //  1,048,576
  float*    Ap1   = (float*)   (ws + 20447232ull);    //  4,194,304 (global, all quarters)
  float*    Bs1   = (float*)   (ws + 24641536ull);    //  4,194,304
  float*    hlast = (float*)   (ws + 28835840ull);    //     32,768
  uint32_t* ab    = (uint32_t*)(ws + 28868608ull);    // 67,108,864 (quarter-local)

  embq_kernel<<<8000, 256, 0, stream>>>(emb, embq);
  wt_kernel<<<1024, 256, 0, stream>>>(Wz, Wh, WtS);

  for (int q = 0; q < 4; q++) {
    const int* xq = x + (size_t)q * QB2 * SEQ;
    gru_kernel<0><<<QBLK, 256, 0, stream>>>(
        xq, embq, WtS, bz, bh, bz + 256, bh + 256, nullptr, ab, Ap0, Bs0);
    scan2_l0<<<QB2, 256, 0, stream>>>(Ap0, Bs0, carry);
    gru_kernel<1><<<QBLK, 256, 0, stream>>>(
        xq, embq, WtS, bz, bh, bz + 256, bh + 256, carry, ab,
        Ap1 + (size_t)q * QBLK * 256, Bs1 + (size_t)q * QBLK * 256);
  }

  scan2_l1<<<32, 256, 0, stream>>>(Ap1, Bs1, hlast);
  cls_kernel<<<1, 256, 0, stream>>>(hlast, Wo, bo, out);
}

// Round 24
// 259.470 us; speedup vs baseline: 1.1607x; 1.1607x over previous
//
#include <hip/hip_runtime.h>
#include <stdint.h>

#define SEQ 8192
#define CS 64                       // chunk length == block row tile
#define NCH 128                     // chunks per sequence
#define HB2 16                      // batches per half
#define HBLK (HB2 * NCH)            // 2048 blocks per half dispatch

typedef float f32x4 __attribute__((ext_vector_type(4)));
typedef short short8 __attribute__((ext_vector_type(8)));
typedef unsigned short u16;
typedef u16 ushort8 __attribute__((ext_vector_type(8)));
typedef u16 ushort4v __attribute__((ext_vector_type(4)));
typedef uint32_t uint4v __attribute__((ext_vector_type(4)));

__device__ __forceinline__ u16 f2bf(float f) {
  uint32_t u = __float_as_uint(f);
  u += 0x7fffu + ((u >> 16) & 1u);   // round-to-nearest-even
  return (u16)(u >> 16);
}
__device__ __forceinline__ float bf2f(uint32_t lo16) {
  return __uint_as_float(lo16 << 16);
}

// async 16B global->LDS (lds dest wave-uniform base; HW adds lane*16)
__device__ __forceinline__ void gld16(void* lds, const void* g) {
  __builtin_amdgcn_global_load_lds(
      (const __attribute__((address_space(1))) uint32_t*)g,
      (__attribute__((address_space(3))) uint32_t*)lds, 16, 0, 0);
}

// ---------- emb f32 -> bf16 table (one-time) ----------
__global__ void embq_kernel(const float* __restrict__ emb, u16* __restrict__ embq) {
  int i = (blockIdx.x * 256 + threadIdx.x) * 4;   // 8,192,000 elements exactly
  float4 v = *(const float4*)(emb + i);
  ushort4v p;
  p[0] = f2bf(v.x); p[1] = f2bf(v.y); p[2] = f2bf(v.z); p[3] = f2bf(v.w);
  *(ushort4v*)(embq + i) = p;
}

// ---------- weight preprocess: f32 [l][k][d] -> bf16 swizzled 4KB BK=32 tiles ----------
// WtS: 128 tiles of 4096 BYTES, tile index (mat*4 + dh)*8 + k32, in-tile [64 dloc][32 kl],
// byte = dloc*64 + ((kl*2) ^ (((dloc>>1)&3)<<4)).  mat: 0=Wz l0,1=Wz l1,2=Wh l0,3=Wh l1
__global__ void wt_kernel(const float* __restrict__ Wz, const float* __restrict__ Wh,
                          u16* __restrict__ WtS) {
  int idx = blockIdx.x * 256 + threadIdx.x;   // 4*65536
  int d = idx & 255;
  int k = (idx >> 8) & 255;
  int m = idx >> 16;
  const float* src = (m < 2 ? Wz : Wh) + (size_t)(m & 1) * 65536;
  float v = src[k * 256 + d];
  int dh = d >> 6, dloc = d & 63, k32 = k >> 5, kl = k & 31;
  size_t tile = ((size_t)(m * 4 + dh) * 8 + k32) * 4096;   // BYTES
  size_t byte = (size_t)(dloc * 64 + ((kl * 2) ^ (((dloc >> 1) & 3) << 4)));
  *(u16*)((char*)WtS + tile + byte) = f2bf(v);
}

// ---- stage ONE wave's private 4KB dh-tile (dh = wave id) for (mat, k32): 4 gld16 ----
__device__ __forceinline__ void stage32(char* dst_wave, const char* WtSb, int mat, int k32,
                                        int w, int lane) {
  const char* src = WtSb + ((size_t)((mat * 4 + w) * 8 + k32)) * 4096 + lane * 16;
  #pragma unroll
  for (int i = 0; i < 4; i++)
    gld16(dst_wave + i * 1024, src + i * 1024);
}

// ---- A-fragment load for one k32: 4 m-frags covering all 64 rows ----
__device__ __forceinline__ void load_fa(const u16* As, int k32, int l15, int lg,
                                        short8 (&fa)[4]) {
  const int xm = (l15 & 7) << 4;
  const int kt = k32 >> 1, ks = k32 & 1;
  #pragma unroll
  for (int mi = 0; mi < 4; mi++)
    fa[mi] = *(const short8*)((const char*)As + kt * 8192 +
               (((mi * 16 + l15) * 128 + ks * 64 + lg * 16) ^ xm));
}

// ---- one 32-k MFMA step (16 MFMAs/wave) from the wave's private 4KB B tile ----
__device__ __forceinline__ void mfma_frags(const char* Pw, const short8 (&fa)[4],
    int l15, int lg, f32x4 (&acc)[4][4])
{
  #pragma unroll
  for (int ni = 0; ni < 4; ni++) {
    const int dloc = ni * 16 + l15;
    const int off = dloc * 64 + ((lg * 16) ^ (((dloc >> 1) & 3) << 4));
    short8 fb = *(const short8*)(Pw + off);
    #pragma unroll
    for (int mi = 0; mi < 4; mi++)
      acc[mi][ni] = __builtin_amdgcn_mfma_f32_16x16x32_bf16(fa[mi], fb, acc[mi][ni], 0, 0, 0);
  }
}

// ---- barrier-free tri-buffered counted-vmcnt pipeline (r17/r20 validated) ----
__device__ __forceinline__ void gemm_pipe3(int lsel, const char* WtSb, const u16* As,
    char* Pw, int w, int l15, int lg, int lane,
    f32x4 (&accz)[4][4], f32x4 (&acch)[4][4])
{
  stage32(Pw,         WtSb, lsel,     0, w, lane);   // j=0 (z, k32=0) -> buf0
  stage32(Pw + 16384, WtSb, 2 + lsel, 0, w, lane);   // j=1 (h, k32=0) -> buf1
  short8 fa[4];
  #pragma unroll
  for (int i = 0; i < 16; ++i) {
    if (i < 15) asm volatile("s_waitcnt vmcnt(4)" ::: "memory");
    else        asm volatile("s_waitcnt vmcnt(0)" ::: "memory");
    __builtin_amdgcn_sched_barrier(0);               // keep reads below the wait
    if (i + 2 < 16)
      stage32(Pw + ((i + 2) % 3) * 16384, WtSb,
              ((i + 2) & 1) ? (2 + lsel) : lsel, (i + 2) >> 1, w, lane);
    if ((i & 1) == 0) {
      load_fa(As, i >> 1, l15, lg, fa);
      mfma_frags(Pw + (i % 3) * 16384, fa, l15, lg, accz);
    } else {
      mfma_frags(Pw + (i % 3) * 16384, fa, l15, lg, acch);
    }
  }
}

// SegT addressing (overlays As): seg row 2048B, XOR-swizzled by seg to spread banks
__device__ __forceinline__ float2* seg_ptr(char* segt, int s, int d) {
  return (float2*)(segt + s * 2048 + ((d * 8) ^ (s << 4)));
}

// ab layout (vectorized, r-in-low-bits; bijective over 16384):
//   t = mi*16 + lg*4 + r,  d = w*64 + ni*16 + l15
//   L = (mi*16 + ni*4 + w)*256 + (lg*16 + l15)*4 + r   (u32 units)
// -> store: one dwordx4 per (mi,ni) per thread, wave covers 1KB contiguous.
// -> rebuild (thread d): uint4 at base + mi*4096 + lg*64, t-order = mi,lg,r sequential.

// ---------- unified GEMM kernel (per-half) ----------
// Block: 256 threads (4 waves; wave w owns ALL 64 rows x cols [64w, 64w+64)), K=256.
// PHASE 0: embq gather -> gemm0 -> gates -> packed ab STORE + chunk totals -> Ap0/Bs0.
// PHASE 1: rebuild h1 from ab+carry (serial per channel) -> gemm1 -> gates -> Ap1/Bs1.
template<int PHASE>
__global__ __launch_bounds__(256, 2)
void gru_kernel(const int* __restrict__ x, const u16* __restrict__ embq,
                const u16* __restrict__ WtS,
                const float* __restrict__ bz0, const float* __restrict__ bh0,
                const float* __restrict__ bz1, const float* __restrict__ bh1,
                const float* __restrict__ carry, uint32_t* __restrict__ ab,
                float* __restrict__ Ap, float* __restrict__ Bs)
{
  __shared__ __align__(16) u16 As[16384];    // 32KB: 4 kt-subtiles [64t][64k] swz; SegT overlay
  __shared__ __align__(16) char Pb[49152];   // 48KB: 3 bufs x (4 waves x 4KB private)

  const int tid = threadIdx.x;
  const int lane = tid & 63;
  const int w = tid >> 6;                    // wave = col-group, owns d in [64w, 64w+64)
  const int l15 = lane & 15, lg = lane >> 4;
  const int cb = blockIdx.x;                 // 0..HBLK-1 (local to half)
  const int b = cb >> 7, c = cb & (NCH - 1);
  const char* WtSb = (const char*)WtS;
  char* segt = (char*)As;
  char* Pw = Pb + w * 4096;                  // wave's private region within each 16KB buf

  f32x4 accz[4][4], acch[4][4];
  #pragma unroll
  for (int i = 0; i < 4; i++)
    #pragma unroll
    for (int j = 0; j < 4; j++) {
      f32x4 zz = {0.f, 0.f, 0.f, 0.f};
      accz[i][j] = zz; acch[i][j] = zz;
    }

  if (PHASE == 0) {
    // ---- A gather: 64 rows x 256 k; thread = (row sm=tid>>2, 64-k quarter kq=tid&3) ----
    {
      const int sm = tid >> 2, kq = tid & 3;
      const int tok = x[b * SEQ + c * CS + sm];
      const u16* src = embq + (size_t)tok * 256 + kq * 64;
      char* sub = (char*)As + kq * 8192;
      const int swz = (sm & 7) << 4;
      #pragma unroll
      for (int j = 0; j < 8; j++) {
        ushort8 p = *(const ushort8*)(src + j * 8);
        *(ushort8*)(sub + ((sm * 128 + j * 16) ^ swz)) = p;
      }
    }
    __syncthreads();                         // As ready (drains vmcnt -> 0 at pipe entry)
    gemm_pipe3(0, WtSb, As, Pw, w, l15, lg, lane, accz, acch);
    __syncthreads();                         // all MFMA done; As free for SegT

    // ---- gates -> vectorized ab store + per-segment (A,B) -> SegT ----
    #pragma unroll
    for (int ni = 0; ni < 4; ni++) {
      const int d = w * 64 + ni * 16 + l15;
      const float bzv = bz0[d];
      const float bhv = bh0[d];
      #pragma unroll
      for (int mi = 0; mi < 4; mi++) {
        float A = 1.f, B = 0.f;
        uint4v pk4;
        #pragma unroll
        for (int r = 0; r < 4; r++) {
          float zl = accz[mi][ni][r] + bzv;
          float a = __builtin_amdgcn_rcpf(1.f + __expf(zl));   // 1 - sigmoid(zl)
          float ht = acch[mi][ni][r] + bhv;
          float bb = (1.f - a) * ht;
          pk4[r] = (uint32_t)f2bf(a) | ((uint32_t)f2bf(bb) << 16);
          B = B * a + bb;
          A *= a;
        }
        *(uint4v*)(ab + (size_t)cb * 16384 +
                   (size_t)((mi * 16 + ni * 4 + w) * 256 + (lg * 16 + l15) * 4)) = pk4;
        *seg_ptr(segt, mi * 4 + lg, d) = make_float2(A, B);    // seg = t/4
      }
    }
    __syncthreads();                         // SegT complete
    {
      float PA = 1.f, PB = 0.f;              // all 256 threads: d = tid
      #pragma unroll
      for (int s = 0; s < 16; s++) {
        float2 v = *seg_ptr(segt, s, tid);
        PB = v.x * PB + v.y;
        PA *= v.x;
      }
      Ap[(size_t)cb * 256 + tid] = PA;
      Bs[(size_t)cb * 256 + tid] = PB;
    }
    return;
  }

  // ================= PHASE 1 =================
  // ---- rebuild h1 tile into As from ab + carry (thread owns channel d = tid) ----
  {
    const int d = tid;
    const int wq = d >> 6, niq = (d >> 4) & 3, l15q = d & 15;
    float h = carry[(size_t)cb * 256 + d];
    const uint32_t* pab = ab + (size_t)cb * 16384 +
                          (size_t)((niq * 4 + wq) * 256 + l15q * 4);
    char* sub = (char*)As + wq * 8192;
    const int kl2 = (d & 63) * 2;
    #pragma unroll
    for (int mi = 0; mi < 4; mi++) {
      #pragma unroll
      for (int lgq = 0; lgq < 4; lgq++) {
        uint4v u4 = *(const uint4v*)(pab + mi * 4096 + lgq * 64);
        #pragma unroll
        for (int r = 0; r < 4; r++) {
          uint32_t u = u4[r];
          h = bf2f(u & 0xffffu) * h + bf2f(u >> 16);
          const int t = mi * 16 + lgq * 4 + r;
          *(u16*)(sub + ((t * 128 + kl2) ^ ((t & 7) << 4))) = f2bf(h);
        }
      }
    }
  }
  __syncthreads();                           // h-tile ready (drains vmcnt -> 0)
  gemm_pipe3(1, WtSb, As, Pw, w, l15, lg, lane, accz, acch);
  __syncthreads();                           // As free for SegT

  // ---- layer-1 gates -> SegT -> totals -> Ap1/Bs1 ----
  #pragma unroll
  for (int ni = 0; ni < 4; ni++) {
    const int d = w * 64 + ni * 16 + l15;
    const float bzv = bz1[d];
    const float bhv = bh1[d];
    #pragma unroll
    for (int mi = 0; mi < 4; mi++) {
      float A = 1.f, B = 0.f;
      #pragma unroll
      for (int r = 0; r < 4; r++) {
        float zl = accz[mi][ni][r] + bzv;
        float a = __builtin_amdgcn_rcpf(1.f + __expf(zl));
        float ht = acch[mi][ni][r] + bhv;
        float bb = (1.f - a) * ht;
        B = B * a + bb;
        A *= a;
      }
      *seg_ptr(segt, mi * 4 + lg, d) = make_float2(A, B);
    }
  }
  __syncthreads();
  {
    float PA = 1.f, PB = 0.f;
    #pragma unroll
    for (int s = 0; s < 16; s++) {
      float2 v = *seg_ptr(segt, s, tid);
      PB = v.x * PB + v.y;
      PA *= v.x;
    }
    Ap[(size_t)cb * 256 + tid] = PA;
    Bs[(size_t)cb * 256 + tid] = PB;
  }
}

// ---------- serial cross-chunk compose for one half (16 batches) ----------
__global__ void scan2_l0(const float* __restrict__ Ap0, const float* __restrict__ Bs0,
                         float* __restrict__ carry) {
  const int g = blockIdx.x * 256 + threadIdx.x;   // 4096 = 16 b * 256 d
  const int b = g >> 8, d = g & 255;
  float h = 0.f;
  for (int c = 0; c < NCH; c++) {
    const size_t idx = (size_t)(b * NCH + c) * 256 + d;
    carry[idx] = h;
    h = Bs0[idx] + Ap0[idx] * h;
  }
}

// ---------- layer-1 final: serial over chunk locals -> hlast (all 32 batches) ----------
__global__ void scan2_l1(const float* __restrict__ Ap1, const float* __restrict__ Bs1,
                         float* __restrict__ hlast) {
  const int g = blockIdx.x * 256 + threadIdx.x;   // 8192
  const int b = g >> 8, d = g & 255;
  float h = 0.f;
  for (int c = 0; c < NCH; c++) {
    const size_t idx = (size_t)(b * NCH + c) * 256 + d;
    h = Bs1[idx] + Ap1[idx] * h;
  }
  hlast[b * 256 + d] = h;
}

__global__ void cls_kernel(const float* __restrict__ hlast, const float* __restrict__ Wo,
                           const float* __restrict__ bo, float* __restrict__ out) {
  const int t = threadIdx.x;       // 256 = 32 b * 8 classes
  const int b = t >> 3, c = t & 7;
  float acc = bo[c];
  for (int d = 0; d < 256; d++) acc += hlast[b * 256 + d] * Wo[d * 8 + c];
  out[t] = acc;
}

extern "C" void kernel_launch(void* const* d_in, const int* in_sizes, int n_in,
                              void* d_out, int out_size, void* d_ws, size_t ws_size,
                              hipStream_t stream) {
  (void)in_sizes; (void)n_in; (void)out_size; (void)ws_size;
  const int*   x   = (const int*)d_in[0];
  const float* emb = (const float*)d_in[1];
  const float* Wz  = (const float*)d_in[2];
  const float* bz  = (const float*)d_in[3];
  const float* Wh  = (const float*)d_in[4];
  const float* bh  = (const float*)d_in[5];
  const float* Wo  = (const float*)d_in[6];
  const float* bo  = (const float*)d_in[7];
  float* out = (float*)d_out;
  char* ws = (char*)d_ws;

  // workspace (~166 MB; ws = 256 MiB)
  u16*      embq  = (u16*)     (ws);                  // 16,384,000 (pad to 16 MiB)
  u16*      WtS   = (u16*)     (ws + 16777216ull);    //    524,288
  float*    Ap0   = (float*)   (ws + 17301504ull);    //  2,097,152 (half-local)
  float*    Bs0   = (float*)   (ws + 19398656ull);    //  2,097,152
  float*    carry = (float*)   (ws + 21495808ull);    //  2,097,152
  float*    Ap1   = (float*)   (ws + 23592960ull);    //  4,194,304 (global, both halves)
  float*    Bs1   = (float*)   (ws + 27787264ull);    //  4,194,304
  float*    hlast = (float*)   (ws + 31981568ull);    //     32,768
  uint32_t* ab    = (uint32_t*)(ws + 32014336ull);    // 134,217,728 (half-local)

  embq_kernel<<<8000, 256, 0, stream>>>(emb, embq);
  wt_kernel<<<1024, 256, 0, stream>>>(Wz, Wh, WtS);

  for (int hf = 0; hf < 2; hf++) {
    const int* xh = x + (size_t)hf * HB2 * SEQ;
    gru_kernel<0><<<HBLK, 256, 0, stream>>>(
        xh, embq, WtS, bz, bh, bz + 256, bh + 256, nullptr, ab, Ap0, Bs0);
    scan2_l0<<<HB2, 256, 0, stream>>>(Ap0, Bs0, carry);
    gru_kernel<1><<<HBLK, 256, 0, stream>>>(
        xh, embq, WtS, bz, bh, bz + 256, bh + 256, carry, ab,
        Ap1 + (size_t)hf * HBLK * 256, Bs1 + (size_t)hf * HBLK * 256);
  }

  scan2_l1<<<32, 256, 0, stream>>>(Ap1, Bs1, hlast);
  cls_kernel<<<1, 256, 0, stream>>>(hlast, Wo, bo, out);
}